// Round 2
// baseline (517.833 us; speedup 1.0000x reference)
//
#include <hip/hip_runtime.h>

typedef unsigned short u16;
typedef __attribute__((ext_vector_type(4))) float f32x4;
typedef __attribute__((ext_vector_type(8))) short s16x8;
typedef __attribute__((ext_vector_type(4))) u16 u16x4;

#define AS1 __attribute__((address_space(1)))
#define AS3 __attribute__((address_space(3)))

__device__ inline u16 f2bf(float f) {
  union { float f; unsigned u; } v; v.f = f;
  unsigned r = v.u + 0x7FFFu + ((v.u >> 16) & 1u);
  return (u16)(r >> 16);
}
__device__ inline float bf2f(u16 h) {
  union { unsigned u; float f; } v; v.u = ((unsigned)h) << 16; return v.f;
}

__device__ inline float redsum16(float v) {
  v += __shfl_xor(v, 1); v += __shfl_xor(v, 2);
  v += __shfl_xor(v, 4); v += __shfl_xor(v, 8);
  return v;
}
__device__ inline float redmax16(float v) {
  v = fmaxf(v, __shfl_xor(v, 1)); v = fmaxf(v, __shfl_xor(v, 2));
  v = fmaxf(v, __shfl_xor(v, 4)); v = fmaxf(v, __shfl_xor(v, 8));
  return v;
}
__device__ inline float redsum64(float v) {
  v += __shfl_xor(v, 1); v += __shfl_xor(v, 2); v += __shfl_xor(v, 4);
  v += __shfl_xor(v, 8); v += __shfl_xor(v, 16); v += __shfl_xor(v, 32);
  return v;
}

// ---------------- cast x to bf16 ----------------
__global__ void cast_x_kernel(const float* __restrict__ x, u16* __restrict__ xbf, int n4) {
  int i = blockIdx.x * blockDim.x + threadIdx.x;
  if (i < n4) {
    f32x4 v = ((const f32x4*)x)[i];
    u16x4 o; o.x = f2bf(v.x); o.y = f2bf(v.y); o.z = f2bf(v.z); o.w = f2bf(v.w);
    ((u16x4*)xbf)[i] = o;
  }
}

// ---------------- rope table: cos/sin [T=2048][32] ----------------
__global__ void rope_table_kernel(float* __restrict__ cosT, float* __restrict__ sinT) {
  int idx = blockIdx.x * 256 + threadIdx.x; // 65536 = 2048*32
  int t = idx >> 5, i = idx & 31;
  float invf = (float)pow(10000.0, -(double)i / 32.0);
  float freq = (float)t * invf;
  cosT[idx] = (float)cos((double)freq);
  sinT[idx] = (float)sin((double)freq);
}

// ---------------- fuse W + A@B, write transposed bf16 [N][2048] ----------------
__global__ void fuse_w_kernel(const float* __restrict__ W, const float* __restrict__ A,
                              const float* __restrict__ Bl, u16* __restrict__ dstT, int N) {
  __shared__ float tile[32][33];
  int k0 = blockIdx.x * 32, n0 = blockIdx.y * 32;
  int tx = threadIdx.x, ty = threadIdx.y; // (32,8)
  #pragma unroll
  for (int i = 0; i < 4; i++) {
    int row = k0 + ty + i * 8;
    float s = W[(size_t)row * N + n0 + tx];
    #pragma unroll
    for (int r = 0; r < 16; r++) s += A[row * 16 + r] * Bl[r * N + n0 + tx];
    tile[ty + i * 8][tx] = s;
  }
  __syncthreads();
  #pragma unroll
  for (int i = 0; i < 4; i++) {
    int n = n0 + ty + i * 8;
    dstT[(size_t)n * 2048 + k0 + tx] = f2bf(tile[tx][ty + i * 8]);
  }
}

// ---------------- GEMM: C[M][N] fp32 = A[M][K]bf16 * BT[N][K]bf16 ----------------
__global__ __launch_bounds__(256) void gemm_kernel(const u16* __restrict__ A,
    const u16* __restrict__ BT, float* __restrict__ C, int M, int N, int K) {
  __shared__ __attribute__((aligned(16))) u16 As[128 * 32];
  __shared__ __attribute__((aligned(16))) u16 Bs[128 * 32];
  const int tid = threadIdx.x;
  const int lane = tid & 63, wave = tid >> 6;
  const int wr = wave >> 1, wc = wave & 1;
  const int m0 = blockIdx.x * 128, n0 = blockIdx.y * 128;
  f32x4 acc[4][4] = {};
  const int lrow = tid >> 2, lseg = tid & 3; // staging: 16B per thread
  for (int k0 = 0; k0 < K; k0 += 32) {
    __syncthreads();
    #pragma unroll
    for (int r = 0; r < 2; r++) {
      const u16* gA = A + (size_t)(m0 + r * 64 + lrow) * K + k0 + lseg * 8;
      __builtin_amdgcn_global_load_lds((const AS1 void*)gA,
          (AS3 void*)(As + r * 2048 + wave * 512), 16, 0, 0);
      const u16* gB = BT + (size_t)(n0 + r * 64 + lrow) * K + k0 + lseg * 8;
      __builtin_amdgcn_global_load_lds((const AS1 void*)gB,
          (AS3 void*)(Bs + r * 2048 + wave * 512), 16, 0, 0);
    }
    __syncthreads();
    s16x8 af[4], bfr[4];
    #pragma unroll
    for (int m = 0; m < 4; m++)
      af[m] = *(const s16x8*)(As + (wr * 64 + m * 16 + (lane & 15)) * 32 + (lane >> 4) * 8);
    #pragma unroll
    for (int n = 0; n < 4; n++)
      bfr[n] = *(const s16x8*)(Bs + (wc * 64 + n * 16 + (lane & 15)) * 32 + (lane >> 4) * 8);
    #pragma unroll
    for (int m = 0; m < 4; m++)
      #pragma unroll
      for (int n = 0; n < 4; n++)
        acc[m][n] = __builtin_amdgcn_mfma_f32_16x16x32_bf16(af[m], bfr[n], acc[m][n], 0, 0, 0);
  }
  #pragma unroll
  for (int m = 0; m < 4; m++) {
    int row = m0 + wr * 64 + m * 16 + (lane >> 4) * 4;
    #pragma unroll
    for (int n = 0; n < 4; n++) {
      int col = n0 + wc * 64 + n * 16 + (lane & 15);
      float* cp = C + (size_t)row * N + col;
      #pragma unroll
      for (int j = 0; j < 4; j++) cp[(size_t)j * N] = acc[m][n][j];
    }
  }
}

// ---------------- RMSnorm + RoPE + gain for q,k; write bf16 (b,h,t,d) ----------------
__global__ __launch_bounds__(256) void qkpost_kernel(const float* __restrict__ QKV,
    const float* __restrict__ cosT, const float* __restrict__ sinT,
    const float* __restrict__ qgain, u16* __restrict__ Qbf, u16* __restrict__ Kbf) {
  int bt = blockIdx.x; int b = bt >> 11, t = bt & 2047;
  int lane = threadIdx.x & 63, wave = threadIdx.x >> 6;
  for (int u = wave; u < 20; u += 4) {
    const float* src = (u < 16) ? (QKV + (size_t)bt * 3072 + u * 128)
                                : (QKV + (size_t)bt * 3072 + 2048 + (u - 16) * 128);
    float x0 = src[lane], x1 = src[lane + 64];
    float ss = redsum64(x0 * x0 + x1 * x1);
    float r = 1.0f / sqrtf(ss * (1.0f / 128.0f) + 1.1920929e-7f);
    x0 *= r; x1 *= r;
    // rope: dims 0..63 live in x0 across the 64 lanes
    float partner = __shfl_xor(x0, 32);
    int i = lane & 31;
    float c = cosT[t * 32 + i], s = sinT[t * 32 + i];
    x0 = x0 * c + ((lane < 32) ? partner * s : -partner * s);
    if (u < 16) {
      float g = qgain[u]; x0 *= g; x1 *= g;
      u16* dst = Qbf + ((size_t)(b * 16 + u) * 2048 + t) * 128;
      dst[lane] = f2bf(x0); dst[lane + 64] = f2bf(x1);
    } else {
      u16* dst = Kbf + ((size_t)(b * 4 + (u - 16)) * 2048 + t) * 128;
      dst[lane] = f2bf(x0); dst[lane + 64] = f2bf(x1);
    }
  }
}

// ---------------- transpose V into (b,kh,d,t) bf16 ----------------
__global__ void transv_kernel(const float* __restrict__ QKV, u16* __restrict__ Vt) {
  __shared__ float tile[32][33];
  int t0 = blockIdx.x * 32, d0 = blockIdx.y * 32, bh = blockIdx.z;
  int b = bh >> 2, kh = bh & 3;
  int tx = threadIdx.x, ty = threadIdx.y;
  #pragma unroll
  for (int i = 0; i < 4; i++) {
    int t = t0 + ty + i * 8;
    tile[ty + i * 8][tx] = QKV[((size_t)(b * 2048 + t)) * 3072 + 2560 + kh * 128 + d0 + tx];
  }
  __syncthreads();
  #pragma unroll
  for (int i = 0; i < 4; i++) {
    int d = d0 + ty + i * 8;
    Vt[((size_t)bh * 128 + d) * 2048 + t0 + tx] = f2bf(tile[tx][ty + i * 8]);
  }
}

// ---------------- flash attention: causal GQA ----------------
__global__ __launch_bounds__(256) void attn_kernel(
    const u16* __restrict__ Qbf, const u16* __restrict__ Kbf,
    const u16* __restrict__ Vt, u16* __restrict__ Ybf) {
  __shared__ __attribute__((aligned(16))) u16 Ks[64 * 128];   // [kv][d]  ^((kv&7)<<4)
  __shared__ __attribute__((aligned(16))) u16 Vts[128 * 64];  // [d][kv]  ^((d&7)<<4)
  __shared__ __attribute__((aligned(16))) u16 Pl[4][16 * 64]; // per-wave [qr][kv] ^((qr&7)<<4)
  int qi = blockIdx.x, h = blockIdx.y, b = blockIdx.z;
  int kh = h >> 2;
  int tid = threadIdx.x, lane = tid & 63, wave = tid >> 6;
  int qbase = qi * 64;
  const u16* Qg = Qbf + ((size_t)(b * 16 + h) * 2048) * 128;
  const u16* Kg = Kbf + ((size_t)(b * 4 + kh) * 2048) * 128;
  const u16* Vg = Vt + ((size_t)(b * 4 + kh) * 128) * 2048;
  int qrow = qbase + wave * 16 + (lane & 15);
  s16x8 qf[4];
  #pragma unroll
  for (int kb = 0; kb < 4; kb++)
    qf[kb] = *(const s16x8*)(Qg + (size_t)qrow * 128 + kb * 32 + (lane >> 4) * 8);
  float m_run[4], l_run[4];
  f32x4 yacc[8] = {};
  #pragma unroll
  for (int j = 0; j < 4; j++) { m_run[j] = -INFINITY; l_run[j] = 0.0f; }
  const float scale = 0.08838834764831845f;
  for (int kv0 = 0; kv0 <= qbase + 63; kv0 += 64) {
    __syncthreads();
    #pragma unroll
    for (int it = 0; it < 4; it++) {
      int u = it * 256 + tid;
      int krow = u >> 4, kseg = u & 15;
      int kbyte = (krow * 256 + kseg * 16) ^ ((krow & 7) << 4);
      *(f32x4*)((char*)Ks + kbyte) = *(const f32x4*)(Kg + (size_t)(kv0 + krow) * 128 + kseg * 8);
      int d = u >> 3, vseg = u & 7;
      int vbyte = (d * 128 + vseg * 16) ^ ((d & 7) << 4);
      *(f32x4*)((char*)Vts + vbyte) = *(const f32x4*)(Vg + (size_t)d * 2048 + kv0 + vseg * 8);
    }
    __syncthreads();
    // QK^T
    f32x4 S[4];
    #pragma unroll
    for (int nb = 0; nb < 4; nb++) {
      int kcol = nb * 16 + (lane & 15);
      f32x4 s = {};
      #pragma unroll
      for (int kb = 0; kb < 4; kb++) {
        int byt = (kcol * 256 + kb * 64 + (lane >> 4) * 16) ^ ((kcol & 7) << 4);
        s16x8 kf = *(const s16x8*)((const char*)Ks + byt);
        s = __builtin_amdgcn_mfma_f32_16x16x32_bf16(qf[kb], kf, s, 0, 0, 0);
      }
      S[nb] = s;
    }
    // mask + scale + row max
    float tmax[4];
    #pragma unroll
    for (int j = 0; j < 4; j++) tmax[j] = -INFINITY;
    #pragma unroll
    for (int nb = 0; nb < 4; nb++) {
      int kcol = kv0 + nb * 16 + (lane & 15);
      #pragma unroll
      for (int j = 0; j < 4; j++) {
        int qr = qbase + wave * 16 + (lane >> 4) * 4 + j;
        float v = S[nb][j] * scale;
        v = (kcol <= qr) ? v : -INFINITY;
        S[nb][j] = v;
        tmax[j] = fmaxf(tmax[j], v);
      }
    }
    float alpha[4], msafe[4], rsum[4];
    #pragma unroll
    for (int j = 0; j < 4; j++) {
      tmax[j] = redmax16(tmax[j]);
      float mn = fmaxf(m_run[j], tmax[j]);
      msafe[j] = (mn == -INFINITY) ? 0.0f : mn;
      alpha[j] = __expf(m_run[j] - msafe[j]);
      m_run[j] = mn;
      rsum[j] = 0.0f;
    }
    // P = exp(S - m), to LDS as bf16
    #pragma unroll
    for (int nb = 0; nb < 4; nb++) {
      #pragma unroll
      for (int j = 0; j < 4; j++) {
        float p = __expf(S[nb][j] - msafe[j]);
        rsum[j] += p;
        int prow = (lane >> 4) * 4 + j, pcol = nb * 16 + (lane & 15);
        int pbyte = (prow * 128 + pcol * 2) ^ ((prow & 7) << 4);
        *(u16*)((char*)Pl[wave] + pbyte) = f2bf(p);
      }
    }
    #pragma unroll
    for (int j = 0; j < 4; j++) {
      rsum[j] = redsum16(rsum[j]);
      l_run[j] = l_run[j] * alpha[j] + rsum[j];
    }
    #pragma unroll
    for (int nb = 0; nb < 8; nb++)
      #pragma unroll
      for (int j = 0; j < 4; j++) yacc[nb][j] *= alpha[j];
    // PV
    s16x8 pa[2];
    #pragma unroll
    for (int k2 = 0; k2 < 2; k2++) {
      int prow = lane & 15;
      int pbyte = (prow * 128 + k2 * 64 + (lane >> 4) * 16) ^ ((prow & 7) << 4);
      pa[k2] = *(const s16x8*)((const char*)Pl[wave] + pbyte);
    }
    #pragma unroll
    for (int nb = 0; nb < 8; nb++) {
      f32x4 y = yacc[nb];
      #pragma unroll
      for (int k2 = 0; k2 < 2; k2++) {
        int d = nb * 16 + (lane & 15);
        int vbyte = (d * 128 + k2 * 64 + (lane >> 4) * 16) ^ ((d & 7) << 4);
        s16x8 vf = *(const s16x8*)((const char*)Vts + vbyte);
        y = __builtin_amdgcn_mfma_f32_16x16x32_bf16(pa[k2], vf, y, 0, 0, 0);
      }
      yacc[nb] = y;
    }
  }
  #pragma unroll
  for (int j = 0; j < 4; j++) {
    float inv = 1.0f / l_run[j];
    int qr = qbase + wave * 16 + (lane >> 4) * 4 + j;
    size_t ybase = ((size_t)(b * 16 + h) * 2048 + qr) * 128;
    #pragma unroll
    for (int nb = 0; nb < 8; nb++)
      Ybf[ybase + nb * 16 + (lane & 15)] = f2bf(yacc[nb][j] * inv);
  }
}

// ---------------- projection removal: y - (y.vn)vn; write (b,t,h*128+d) bf16 ----------------
__global__ __launch_bounds__(256) void projrm_kernel(const float* __restrict__ QKV,
    const u16* __restrict__ Ybf, u16* __restrict__ Yout) {
  int bt = blockIdx.x;
  int b = bt >> 11, t = bt & 2047;
  int lane = threadIdx.x & 63, kh = threadIdx.x >> 6;
  const float* v = QKV + (size_t)bt * 3072 + 2560 + kh * 128;
  float v0 = v[lane], v1 = v[lane + 64];
  float sv = redsum64(v0 * v0 + v1 * v1);
  float denom = fmaxf(sqrtf(sv), 1e-12f);
  float inv2 = 1.0f / (denom * denom);
  #pragma unroll
  for (int g = 0; g < 4; g++) {
    int h = kh * 4 + g;
    const u16* y = Ybf + ((size_t)(b * 16 + h) * 2048 + t) * 128;
    float y0 = bf2f(y[lane]), y1 = bf2f(y[lane + 64]);
    float c = redsum64(y0 * v0 + y1 * v1) * inv2;
    u16* o = Yout + (size_t)bt * 2048 + h * 128;
    o[lane] = f2bf(y0 - c * v0);
    o[lane + 64] = f2bf(y1 - c * v1);
  }
}

// ---------------- launch ----------------
extern "C" void kernel_launch(void* const* d_in, const int* in_sizes, int n_in,
                              void* d_out, int out_size, void* d_ws, size_t ws_size,
                              hipStream_t stream) {
  const float* x = (const float*)d_in[0];
  const float* Wq = (const float*)d_in[1];
  const float* Wk = (const float*)d_in[2];
  const float* Wv = (const float*)d_in[3];
  const float* Wp = (const float*)d_in[4];
  const float* qgain = (const float*)d_in[5];
  const float* qA = (const float*)d_in[6];
  const float* qB = (const float*)d_in[7];
  const float* kA = (const float*)d_in[8];
  const float* kB = (const float*)d_in[9];
  const float* vA = (const float*)d_in[10];
  const float* vB = (const float*)d_in[11];
  const float* pA = (const float*)d_in[12];
  const float* pB = (const float*)d_in[13];

  char* ws = (char*)d_ws;
  const size_t XBF  = 0;                  // 16777216  x bf16 [4096][2048]
  const size_t WQKV = 16777216;           // 12582912  [3072][2048] bf16 (q|k|v cols transposed)
  const size_t WPE  = 29360128;           // 8388608   [2048][2048] bf16
  const size_t QKV  = 37748736;           // 50331648  fp32 [4096][3072]
  const size_t COS  = 88080384;           // 262144
  const size_t SIN  = 88342528;           // 262144
  const size_t QBF  = 88604672;           // 16777216  (b,h,t,d)
  const size_t KBF  = 105381888;          // 4194304   (b,kh,t,d)
  const size_t VT   = 109576192;          // 4194304   (b,kh,d,t)
  const size_t YBF  = 113770496;          // 16777216  (b,h,t,d)
  const size_t YOUT = 130547712;          // 16777216  (b,t,h*128+d)

  u16* xbf = (u16*)(ws + XBF);
  u16* wqkv = (u16*)(ws + WQKV);
  u16* wpe = (u16*)(ws + WPE);
  float* qkv = (float*)(ws + QKV);
  float* cosT = (float*)(ws + COS);
  float* sinT = (float*)(ws + SIN);
  u16* qbf = (u16*)(ws + QBF);
  u16* kbf = (u16*)(ws + KBF);
  u16* vt = (u16*)(ws + VT);
  u16* ybf = (u16*)(ws + YBF);
  u16* yout = (u16*)(ws + YOUT);

  cast_x_kernel<<<8192, 256, 0, stream>>>(x, xbf, 2097152);
  rope_table_kernel<<<256, 256, 0, stream>>>(cosT, sinT);
  fuse_w_kernel<<<dim3(64, 64), dim3(32, 8), 0, stream>>>(Wq, qA, qB, wqkv, 2048);
  fuse_w_kernel<<<dim3(64, 16), dim3(32, 8), 0, stream>>>(Wk, kA, kB, wqkv + (size_t)2048 * 2048, 512);
  fuse_w_kernel<<<dim3(64, 16), dim3(32, 8), 0, stream>>>(Wv, vA, vB, wqkv + (size_t)2560 * 2048, 512);
  fuse_w_kernel<<<dim3(64, 64), dim3(32, 8), 0, stream>>>(Wp, pA, pB, wpe, 2048);
  gemm_kernel<<<dim3(32, 24), 256, 0, stream>>>(xbf, wqkv, qkv, 4096, 3072, 2048);
  qkpost_kernel<<<4096, 256, 0, stream>>>(qkv, cosT, sinT, qgain, qbf, kbf);
  transv_kernel<<<dim3(64, 4, 8), dim3(32, 8), 0, stream>>>(qkv, vt);
  attn_kernel<<<dim3(32, 16, 2), 256, 0, stream>>>(qbf, kbf, vt, ybf);
  projrm_kernel<<<4096, 256, 0, stream>>>(qkv, ybf, yout);
  gemm_kernel<<<dim3(32, 16), 256, 0, stream>>>(yout, wpe, (float*)d_out, 4096, 2048, 2048);
}

// Round 3
// 478.489 us; speedup vs baseline: 1.0822x; 1.0822x over previous
//
#include <hip/hip_runtime.h>

typedef unsigned short u16;
typedef __attribute__((ext_vector_type(4))) float f32x4;
typedef __attribute__((ext_vector_type(8))) short s16x8;
typedef __attribute__((ext_vector_type(4))) u16 u16x4;

#define AS1 __attribute__((address_space(1)))
#define AS3 __attribute__((address_space(3)))

__device__ inline u16 f2bf(float f) {
  union { float f; unsigned u; } v; v.f = f;
  unsigned r = v.u + 0x7FFFu + ((v.u >> 16) & 1u);
  return (u16)(r >> 16);
}
__device__ inline float bf2f(u16 h) {
  union { unsigned u; float f; } v; v.u = ((unsigned)h) << 16; return v.f;
}

__device__ inline float redsum16(float v) {
  v += __shfl_xor(v, 1); v += __shfl_xor(v, 2);
  v += __shfl_xor(v, 4); v += __shfl_xor(v, 8);
  return v;
}
__device__ inline float redmax16(float v) {
  v = fmaxf(v, __shfl_xor(v, 1)); v = fmaxf(v, __shfl_xor(v, 2));
  v = fmaxf(v, __shfl_xor(v, 4)); v = fmaxf(v, __shfl_xor(v, 8));
  return v;
}
__device__ inline float redsum64(float v) {
  v += __shfl_xor(v, 1); v += __shfl_xor(v, 2); v += __shfl_xor(v, 4);
  v += __shfl_xor(v, 8); v += __shfl_xor(v, 16); v += __shfl_xor(v, 32);
  return v;
}

// ---------------- cast x to bf16 ----------------
__global__ void cast_x_kernel(const float* __restrict__ x, u16* __restrict__ xbf, int n4) {
  int i = blockIdx.x * blockDim.x + threadIdx.x;
  if (i < n4) {
    f32x4 v = ((const f32x4*)x)[i];
    u16x4 o; o.x = f2bf(v.x); o.y = f2bf(v.y); o.z = f2bf(v.z); o.w = f2bf(v.w);
    ((u16x4*)xbf)[i] = o;
  }
}

// ---------------- rope table: cos/sin [T=2048][32] ----------------
__global__ void rope_table_kernel(float* __restrict__ cosT, float* __restrict__ sinT) {
  int idx = blockIdx.x * 256 + threadIdx.x; // 65536 = 2048*32
  int t = idx >> 5, i = idx & 31;
  float invf = (float)pow(10000.0, -(double)i / 32.0);
  float freq = (float)t * invf;
  cosT[idx] = (float)cos((double)freq);
  sinT[idx] = (float)sin((double)freq);
}

// ---------------- fuse W + A@B, write transposed bf16 [N][2048] ----------------
__global__ void fuse_w_kernel(const float* __restrict__ W, const float* __restrict__ A,
                              const float* __restrict__ Bl, u16* __restrict__ dstT, int N) {
  __shared__ float tile[32][33];
  int k0 = blockIdx.x * 32, n0 = blockIdx.y * 32;
  int tx = threadIdx.x, ty = threadIdx.y; // (32,8)
  #pragma unroll
  for (int i = 0; i < 4; i++) {
    int row = k0 + ty + i * 8;
    float s = W[(size_t)row * N + n0 + tx];
    #pragma unroll
    for (int r = 0; r < 16; r++) s += A[row * 16 + r] * Bl[r * N + n0 + tx];
    tile[ty + i * 8][tx] = s;
  }
  __syncthreads();
  #pragma unroll
  for (int i = 0; i < 4; i++) {
    int n = n0 + ty + i * 8;
    dstT[(size_t)n * 2048 + k0 + tx] = f2bf(tile[tx][ty + i * 8]);
  }
}

// ---------------- GEMM: C[M][N] fp32 = A[M][K]bf16 * BT[N][K]bf16 ----------------
__global__ __launch_bounds__(256) void gemm_kernel(const u16* __restrict__ A,
    const u16* __restrict__ BT, float* __restrict__ C, int M, int N, int K) {
  __shared__ __attribute__((aligned(16))) u16 As[128 * 32];
  __shared__ __attribute__((aligned(16))) u16 Bs[128 * 32];
  const int tid = threadIdx.x;
  const int lane = tid & 63, wave = tid >> 6;
  const int wr = wave >> 1, wc = wave & 1;
  const int m0 = blockIdx.x * 128, n0 = blockIdx.y * 128;
  f32x4 acc[4][4] = {};
  const int lrow = tid >> 2, lseg = tid & 3; // staging: 16B per thread
  for (int k0 = 0; k0 < K; k0 += 32) {
    __syncthreads();
    #pragma unroll
    for (int r = 0; r < 2; r++) {
      const u16* gA = A + (size_t)(m0 + r * 64 + lrow) * K + k0 + lseg * 8;
      __builtin_amdgcn_global_load_lds((const AS1 void*)gA,
          (AS3 void*)(As + r * 2048 + wave * 512), 16, 0, 0);
      const u16* gB = BT + (size_t)(n0 + r * 64 + lrow) * K + k0 + lseg * 8;
      __builtin_amdgcn_global_load_lds((const AS1 void*)gB,
          (AS3 void*)(Bs + r * 2048 + wave * 512), 16, 0, 0);
    }
    __syncthreads();
    s16x8 af[4], bfr[4];
    #pragma unroll
    for (int m = 0; m < 4; m++)
      af[m] = *(const s16x8*)(As + (wr * 64 + m * 16 + (lane & 15)) * 32 + (lane >> 4) * 8);
    #pragma unroll
    for (int n = 0; n < 4; n++)
      bfr[n] = *(const s16x8*)(Bs + (wc * 64 + n * 16 + (lane & 15)) * 32 + (lane >> 4) * 8);
    #pragma unroll
    for (int m = 0; m < 4; m++)
      #pragma unroll
      for (int n = 0; n < 4; n++)
        acc[m][n] = __builtin_amdgcn_mfma_f32_16x16x32_bf16(af[m], bfr[n], acc[m][n], 0, 0, 0);
  }
  #pragma unroll
  for (int m = 0; m < 4; m++) {
    int row = m0 + wr * 64 + m * 16 + (lane >> 4) * 4;
    #pragma unroll
    for (int n = 0; n < 4; n++) {
      int col = n0 + wc * 64 + n * 16 + (lane & 15);
      float* cp = C + (size_t)row * N + col;
      #pragma unroll
      for (int j = 0; j < 4; j++) cp[(size_t)j * N] = acc[m][n][j];
    }
  }
}

// ---------------- RMSnorm + RoPE + gain(+score scale) for q,k; write bf16 ----------------
__global__ __launch_bounds__(256) void qkpost_kernel(const float* __restrict__ QKV,
    const float* __restrict__ cosT, const float* __restrict__ sinT,
    const float* __restrict__ qgain, u16* __restrict__ Qbf, u16* __restrict__ Kbf) {
  int bt = blockIdx.x; int b = bt >> 11, t = bt & 2047;
  int lane = threadIdx.x & 63, wave = threadIdx.x >> 6;
  for (int u = wave; u < 20; u += 4) {
    const float* src = (u < 16) ? (QKV + (size_t)bt * 3072 + u * 128)
                                : (QKV + (size_t)bt * 3072 + 2048 + (u - 16) * 128);
    float x0 = src[lane], x1 = src[lane + 64];
    float ss = redsum64(x0 * x0 + x1 * x1);
    float r = 1.0f / sqrtf(ss * (1.0f / 128.0f) + 1.1920929e-7f);
    x0 *= r; x1 *= r;
    // rope: dims 0..63 live in x0 across the 64 lanes
    float partner = __shfl_xor(x0, 32);
    int i = lane & 31;
    float c = cosT[t * 32 + i], s = sinT[t * 32 + i];
    x0 = x0 * c + ((lane < 32) ? partner * s : -partner * s);
    if (u < 16) {
      float g = qgain[u] * 0.08838834764831845f; // fold score scale into Q
      x0 *= g; x1 *= g;
      u16* dst = Qbf + ((size_t)(b * 16 + u) * 2048 + t) * 128;
      dst[lane] = f2bf(x0); dst[lane + 64] = f2bf(x1);
    } else {
      u16* dst = Kbf + ((size_t)(b * 4 + (u - 16)) * 2048 + t) * 128;
      dst[lane] = f2bf(x0); dst[lane + 64] = f2bf(x1);
    }
  }
}

// ---------------- transpose V into (b,kh,d,t) bf16 ----------------
__global__ void transv_kernel(const float* __restrict__ QKV, u16* __restrict__ Vt) {
  __shared__ float tile[32][33];
  int t0 = blockIdx.x * 32, d0 = blockIdx.y * 32, bh = blockIdx.z;
  int b = bh >> 2, kh = bh & 3;
  int tx = threadIdx.x, ty = threadIdx.y;
  #pragma unroll
  for (int i = 0; i < 4; i++) {
    int t = t0 + ty + i * 8;
    tile[ty + i * 8][tx] = QKV[((size_t)(b * 2048 + t)) * 3072 + 2560 + kh * 128 + d0 + tx];
  }
  __syncthreads();
  #pragma unroll
  for (int i = 0; i < 4; i++) {
    int d = d0 + ty + i * 8;
    Vt[((size_t)bh * 128 + d) * 2048 + t0 + tx] = f2bf(tile[tx][ty + i * 8]);
  }
}

// ---------------- attention helpers ----------------
__device__ __forceinline__ void load_tile(const u16* Kg, const u16* Vg, int kv0,
    int tid, f32x4* kreg, f32x4* vreg) {
  #pragma unroll
  for (int it = 0; it < 4; it++) {
    int u = it * 256 + tid;
    kreg[it] = *(const f32x4*)(Kg + (size_t)(kv0 + (u >> 4)) * 128 + (u & 15) * 8);
    vreg[it] = *(const f32x4*)(Vg + (size_t)(u >> 3) * 2048 + kv0 + (u & 7) * 8);
  }
}
__device__ __forceinline__ void write_tile(u16* Ks, u16* Vts, int tid,
    const f32x4* kreg, const f32x4* vreg) {
  #pragma unroll
  for (int it = 0; it < 4; it++) {
    int u = it * 256 + tid;
    int krow = u >> 4, kseg = u & 15;
    *(f32x4*)((char*)Ks + ((krow * 256 + kseg * 16) ^ ((krow & 7) << 4))) = kreg[it];
    int d = u >> 3, vseg = u & 7;
    *(f32x4*)((char*)Vts + ((d * 128 + vseg * 16) ^ ((d & 7) << 4))) = vreg[it];
  }
}

__device__ __forceinline__ void attn_step(const s16x8* qf, f32x4* yacc,
    float* m_run, float* l_part, const u16* Ks, const u16* Vts, u16* Pbuf,
    int kv0, int qbase, int lane, int wave, bool diag) {
  f32x4 S[4];
  __builtin_amdgcn_s_setprio(1);
  #pragma unroll
  for (int nb = 0; nb < 4; nb++) {
    int kcol = nb * 16 + (lane & 15);
    f32x4 s = {};
    #pragma unroll
    for (int kb = 0; kb < 4; kb++) {
      int byt = (kcol * 256 + kb * 64 + (lane >> 4) * 16) ^ ((kcol & 7) << 4);
      s16x8 kf = *(const s16x8*)((const char*)Ks + byt);
      s = __builtin_amdgcn_mfma_f32_16x16x32_bf16(qf[kb], kf, s, 0, 0, 0);
    }
    S[nb] = s;
  }
  __builtin_amdgcn_s_setprio(0);
  if (diag) {
    #pragma unroll
    for (int nb = 0; nb < 4; nb++) {
      int kcol = kv0 + nb * 16 + (lane & 15);
      #pragma unroll
      for (int jj = 0; jj < 4; jj++) {
        int qr = qbase + wave * 16 + (lane >> 4) * 4 + jj;
        if (kcol > qr) S[nb][jj] = -INFINITY;
      }
    }
  }
  float tmax[4];
  #pragma unroll
  for (int jj = 0; jj < 4; jj++) tmax[jj] = -INFINITY;
  #pragma unroll
  for (int nb = 0; nb < 4; nb++)
    #pragma unroll
    for (int jj = 0; jj < 4; jj++) tmax[jj] = fmaxf(tmax[jj], S[nb][jj]);
  #pragma unroll
  for (int jj = 0; jj < 4; jj++) tmax[jj] = redmax16(tmax[jj]);
  bool need = false;
  #pragma unroll
  for (int jj = 0; jj < 4; jj++) need = need || (tmax[jj] > m_run[jj] + 8.0f);
  if (__any(need)) {
    #pragma unroll
    for (int jj = 0; jj < 4; jj++) {
      float mn = fmaxf(m_run[jj], tmax[jj]);
      float a = __expf(m_run[jj] - mn);
      m_run[jj] = mn; l_part[jj] *= a;
      #pragma unroll
      for (int nb = 0; nb < 8; nb++) yacc[nb][jj] *= a;
    }
  }
  #pragma unroll
  for (int nb = 0; nb < 4; nb++) {
    #pragma unroll
    for (int jj = 0; jj < 4; jj++) {
      float pv = __expf(S[nb][jj] - m_run[jj]);
      l_part[jj] += pv;
      int prow = (lane >> 4) * 4 + jj, pcol = nb * 16 + (lane & 15);
      int pbyte = (prow * 128 + pcol * 2) ^ ((prow & 7) << 4);
      *(u16*)((char*)Pbuf + pbyte) = f2bf(pv);
    }
  }
  s16x8 pa[2];
  #pragma unroll
  for (int k2 = 0; k2 < 2; k2++) {
    int prow = lane & 15;
    int pbyte = (prow * 128 + k2 * 64 + (lane >> 4) * 16) ^ ((prow & 7) << 4);
    pa[k2] = *(const s16x8*)((const char*)Pbuf + pbyte);
  }
  __builtin_amdgcn_s_setprio(1);
  #pragma unroll
  for (int nb = 0; nb < 8; nb++) {
    f32x4 y = yacc[nb];
    #pragma unroll
    for (int k2 = 0; k2 < 2; k2++) {
      int d = nb * 16 + (lane & 15);
      int vbyte = (d * 128 + k2 * 64 + (lane >> 4) * 16) ^ ((d & 7) << 4);
      s16x8 vf = *(const s16x8*)((const char*)Vts + vbyte);
      y = __builtin_amdgcn_mfma_f32_16x16x32_bf16(pa[k2], vf, y, 0, 0, 0);
    }
    yacc[nb] = y;
  }
  __builtin_amdgcn_s_setprio(0);
}

// ---------------- flash attention: causal GQA, folded q-tile pairs ----------------
// block = (pair p, head h, batch b); handles q-tiles p and 31-p; KV tiles shared.
__global__ __launch_bounds__(256, 2) void attn_kernel(
    const u16* __restrict__ Qbf, const u16* __restrict__ Kbf,
    const u16* __restrict__ Vt, u16* __restrict__ Ybf) {
  __shared__ __attribute__((aligned(16))) u16 Ks[64 * 128];      // [kv][d]  ^((kv&7)<<4)
  __shared__ __attribute__((aligned(16))) u16 Vts[128 * 64];     // [d][kv]  ^((d&7)<<4)
  __shared__ __attribute__((aligned(16))) u16 Pl[4][2][1024];    // per-wave, per-tile
  int p = blockIdx.x, h = blockIdx.y, b = blockIdx.z;
  int kh = h >> 2;
  int tid = threadIdx.x, lane = tid & 63, wave = tid >> 6;
  const int qiA = p, qiB = 31 - p;
  const int qbaseA = qiA * 64, qbaseB = qiB * 64;
  const u16* Qg = Qbf + ((size_t)(b * 16 + h) * 2048) * 128;
  const u16* Kg = Kbf + ((size_t)(b * 4 + kh) * 2048) * 128;
  const u16* Vg = Vt + ((size_t)(b * 4 + kh) * 128) * 2048;
  int qrA = qbaseA + wave * 16 + (lane & 15);
  int qrB = qbaseB + wave * 16 + (lane & 15);
  s16x8 qfA[4], qfB[4];
  #pragma unroll
  for (int kb = 0; kb < 4; kb++) {
    qfA[kb] = *(const s16x8*)(Qg + (size_t)qrA * 128 + kb * 32 + (lane >> 4) * 8);
    qfB[kb] = *(const s16x8*)(Qg + (size_t)qrB * 128 + kb * 32 + (lane >> 4) * 8);
  }
  f32x4 yA[8] = {}, yB[8] = {};
  float mA[4], lA[4], mB[4], lB[4];
  #pragma unroll
  for (int jj = 0; jj < 4; jj++) {
    mA[jj] = -INFINITY; lA[jj] = 0.0f; mB[jj] = -INFINITY; lB[jj] = 0.0f;
  }
  f32x4 kreg[4], vreg[4];
  const int jmax = qiB;
  load_tile(Kg, Vg, 0, tid, kreg, vreg);
  write_tile(Ks, Vts, tid, kreg, vreg);
  load_tile(Kg, Vg, 64, tid, kreg, vreg);
  __syncthreads();
  for (int j = 0; j <= jmax; j++) {
    int kv0 = j * 64;
    attn_step(qfB, yB, mB, lB, Ks, Vts, &Pl[wave][1][0], kv0, qbaseB, lane, wave, j == qiB);
    if (j <= qiA)
      attn_step(qfA, yA, mA, lA, Ks, Vts, &Pl[wave][0][0], kv0, qbaseA, lane, wave, j == qiA);
    __syncthreads();
    if (j < jmax) {
      write_tile(Ks, Vts, tid, kreg, vreg);
      if (j + 2 <= jmax) load_tile(Kg, Vg, (j + 2) * 64, tid, kreg, vreg);
    }
    __syncthreads();
  }
  #pragma unroll
  for (int jj = 0; jj < 4; jj++) {
    float linvB = 1.0f / redsum16(lB[jj]);
    int qr = qbaseB + wave * 16 + (lane >> 4) * 4 + jj;
    size_t ybase = ((size_t)(b * 16 + h) * 2048 + qr) * 128;
    #pragma unroll
    for (int nb = 0; nb < 8; nb++)
      Ybf[ybase + nb * 16 + (lane & 15)] = f2bf(yB[nb][jj] * linvB);
  }
  #pragma unroll
  for (int jj = 0; jj < 4; jj++) {
    float linvA = 1.0f / redsum16(lA[jj]);
    int qr = qbaseA + wave * 16 + (lane >> 4) * 4 + jj;
    size_t ybase = ((size_t)(b * 16 + h) * 2048 + qr) * 128;
    #pragma unroll
    for (int nb = 0; nb < 8; nb++)
      Ybf[ybase + nb * 16 + (lane & 15)] = f2bf(yA[nb][jj] * linvA);
  }
}

// ---------------- projection removal: y - (y.vn)vn; write (b,t,h*128+d) bf16 ----------------
__global__ __launch_bounds__(256) void projrm_kernel(const float* __restrict__ QKV,
    const u16* __restrict__ Ybf, u16* __restrict__ Yout) {
  int bt = blockIdx.x;
  int b = bt >> 11, t = bt & 2047;
  int lane = threadIdx.x & 63, kh = threadIdx.x >> 6;
  const float* v = QKV + (size_t)bt * 3072 + 2560 + kh * 128;
  float v0 = v[lane], v1 = v[lane + 64];
  float sv = redsum64(v0 * v0 + v1 * v1);
  float denom = fmaxf(sqrtf(sv), 1e-12f);
  float inv2 = 1.0f / (denom * denom);
  #pragma unroll
  for (int g = 0; g < 4; g++) {
    int h = kh * 4 + g;
    const u16* y = Ybf + ((size_t)(b * 16 + h) * 2048 + t) * 128;
    float y0 = bf2f(y[lane]), y1 = bf2f(y[lane + 64]);
    float c = redsum64(y0 * v0 + y1 * v1) * inv2;
    u16* o = Yout + (size_t)bt * 2048 + h * 128;
    o[lane] = f2bf(y0 - c * v0);
    o[lane + 64] = f2bf(y1 - c * v1);
  }
}

// ---------------- launch ----------------
extern "C" void kernel_launch(void* const* d_in, const int* in_sizes, int n_in,
                              void* d_out, int out_size, void* d_ws, size_t ws_size,
                              hipStream_t stream) {
  const float* x = (const float*)d_in[0];
  const float* Wq = (const float*)d_in[1];
  const float* Wk = (const float*)d_in[2];
  const float* Wv = (const float*)d_in[3];
  const float* Wp = (const float*)d_in[4];
  const float* qgain = (const float*)d_in[5];
  const float* qA = (const float*)d_in[6];
  const float* qB = (const float*)d_in[7];
  const float* kA = (const float*)d_in[8];
  const float* kB = (const float*)d_in[9];
  const float* vA = (const float*)d_in[10];
  const float* vB = (const float*)d_in[11];
  const float* pA = (const float*)d_in[12];
  const float* pB = (const float*)d_in[13];

  char* ws = (char*)d_ws;
  const size_t XBF  = 0;                  // 16777216  x bf16 [4096][2048]
  const size_t WQKV = 16777216;           // 12582912  [3072][2048] bf16 (q|k|v cols transposed)
  const size_t WPE  = 29360128;           // 8388608   [2048][2048] bf16
  const size_t QKV  = 37748736;           // 50331648  fp32 [4096][3072]
  const size_t COS  = 88080384;           // 262144
  const size_t SIN  = 88342528;           // 262144
  const size_t QBF  = 88604672;           // 16777216  (b,h,t,d)
  const size_t KBF  = 105381888;          // 4194304   (b,kh,t,d)
  const size_t VT   = 109576192;          // 4194304   (b,kh,d,t)
  const size_t YBF  = 113770496;          // 16777216  (b,h,t,d)
  const size_t YOUT = 130547712;          // 16777216  (b,t,h*128+d)

  u16* xbf = (u16*)(ws + XBF);
  u16* wqkv = (u16*)(ws + WQKV);
  u16* wpe = (u16*)(ws + WPE);
  float* qkv = (float*)(ws + QKV);
  float* cosT = (float*)(ws + COS);
  float* sinT = (float*)(ws + SIN);
  u16* qbf = (u16*)(ws + QBF);
  u16* kbf = (u16*)(ws + KBF);
  u16* vt = (u16*)(ws + VT);
  u16* ybf = (u16*)(ws + YBF);
  u16* yout = (u16*)(ws + YOUT);

  cast_x_kernel<<<8192, 256, 0, stream>>>(x, xbf, 2097152);
  rope_table_kernel<<<256, 256, 0, stream>>>(cosT, sinT);
  fuse_w_kernel<<<dim3(64, 64), dim3(32, 8), 0, stream>>>(Wq, qA, qB, wqkv, 2048);
  fuse_w_kernel<<<dim3(64, 16), dim3(32, 8), 0, stream>>>(Wk, kA, kB, wqkv + (size_t)2048 * 2048, 512);
  fuse_w_kernel<<<dim3(64, 16), dim3(32, 8), 0, stream>>>(Wv, vA, vB, wqkv + (size_t)2560 * 2048, 512);
  fuse_w_kernel<<<dim3(64, 64), dim3(32, 8), 0, stream>>>(Wp, pA, pB, wpe, 2048);
  gemm_kernel<<<dim3(32, 24), 256, 0, stream>>>(xbf, wqkv, qkv, 4096, 3072, 2048);
  qkpost_kernel<<<4096, 256, 0, stream>>>(qkv, cosT, sinT, qgain, qbf, kbf);
  transv_kernel<<<dim3(64, 4, 8), dim3(32, 8), 0, stream>>>(qkv, vt);
  attn_kernel<<<dim3(16, 16, 2), 256, 0, stream>>>(qbf, kbf, vt, ybf);
  projrm_kernel<<<4096, 256, 0, stream>>>(qkv, ybf, yout);
  gemm_kernel<<<dim3(32, 16), 256, 0, stream>>>(yout, wpe, (float*)d_out, 4096, 2048, 2048);
}

// Round 5
// 413.214 us; speedup vs baseline: 1.2532x; 1.1580x over previous
//
#include <hip/hip_runtime.h>

typedef unsigned short u16;
typedef __attribute__((ext_vector_type(4))) float f32x4;
typedef __attribute__((ext_vector_type(8))) short s16x8;
typedef __attribute__((ext_vector_type(4))) u16 u16x4;

#define AS1 __attribute__((address_space(1)))
#define AS3 __attribute__((address_space(3)))

__device__ inline u16 f2bf(float f) {
  union { float f; unsigned u; } v; v.f = f;
  unsigned r = v.u + 0x7FFFu + ((v.u >> 16) & 1u);
  return (u16)(r >> 16);
}
__device__ inline float bf2f(u16 h) {
  union { unsigned u; float f; } v; v.u = ((unsigned)h) << 16; return v.f;
}

__device__ inline float redsum16(float v) {
  v += __shfl_xor(v, 1); v += __shfl_xor(v, 2);
  v += __shfl_xor(v, 4); v += __shfl_xor(v, 8);
  return v;
}
__device__ inline float redsum64(float v) {
  v += __shfl_xor(v, 1); v += __shfl_xor(v, 2); v += __shfl_xor(v, 4);
  v += __shfl_xor(v, 8); v += __shfl_xor(v, 16); v += __shfl_xor(v, 32);
  return v;
}

// ---------------- cast x to bf16 ----------------
__global__ void cast_x_kernel(const float* __restrict__ x, u16* __restrict__ xbf, int n4) {
  int i = blockIdx.x * blockDim.x + threadIdx.x;
  if (i < n4) {
    f32x4 v = ((const f32x4*)x)[i];
    u16x4 o; o.x = f2bf(v.x); o.y = f2bf(v.y); o.z = f2bf(v.z); o.w = f2bf(v.w);
    ((u16x4*)xbf)[i] = o;
  }
}

// ---------------- rope table: cos/sin [T=2048][32] ----------------
__global__ void rope_table_kernel(float* __restrict__ cosT, float* __restrict__ sinT) {
  int idx = blockIdx.x * 256 + threadIdx.x; // 65536 = 2048*32
  int t = idx >> 5, i = idx & 31;
  float invf = (float)pow(10000.0, -(double)i / 32.0);
  float freq = (float)t * invf;
  cosT[idx] = (float)cos((double)freq);
  sinT[idx] = (float)sin((double)freq);
}

// ---------------- fuse W + A@B, write transposed bf16 [N][2048] ----------------
__global__ void fuse_w_kernel(const float* __restrict__ W, const float* __restrict__ A,
                              const float* __restrict__ Bl, u16* __restrict__ dstT, int N) {
  __shared__ float tile[32][33];
  int k0 = blockIdx.x * 32, n0 = blockIdx.y * 32;
  int tx = threadIdx.x, ty = threadIdx.y; // (32,8)
  #pragma unroll
  for (int i = 0; i < 4; i++) {
    int row = k0 + ty + i * 8;
    float s = W[(size_t)row * N + n0 + tx];
    #pragma unroll
    for (int r = 0; r < 16; r++) s += A[row * 16 + r] * Bl[r * N + n0 + tx];
    tile[ty + i * 8][tx] = s;
  }
  __syncthreads();
  #pragma unroll
  for (int i = 0; i < 4; i++) {
    int n = n0 + ty + i * 8;
    dstT[(size_t)n * 2048 + k0 + tx] = f2bf(tile[tx][ty + i * 8]);
  }
}

// ---------------- GEMM: C[M][N] fp32 = A[M][K]bf16 * BT[N][K]bf16 ----------------
__global__ __launch_bounds__(256) void gemm_kernel(const u16* __restrict__ A,
    const u16* __restrict__ BT, float* __restrict__ C, int M, int N, int K) {
  __shared__ __attribute__((aligned(16))) u16 As[128 * 32];
  __shared__ __attribute__((aligned(16))) u16 Bs[128 * 32];
  const int tid = threadIdx.x;
  const int lane = tid & 63, wave = tid >> 6;
  const int wr = wave >> 1, wc = wave & 1;
  const int m0 = blockIdx.x * 128, n0 = blockIdx.y * 128;
  f32x4 acc[4][4] = {};
  const int lrow = tid >> 2, lseg = tid & 3; // staging: 16B per thread
  for (int k0 = 0; k0 < K; k0 += 32) {
    __syncthreads();
    #pragma unroll
    for (int r = 0; r < 2; r++) {
      const u16* gA = A + (size_t)(m0 + r * 64 + lrow) * K + k0 + lseg * 8;
      __builtin_amdgcn_global_load_lds((const AS1 void*)gA,
          (AS3 void*)(As + r * 2048 + wave * 512), 16, 0, 0);
      const u16* gB = BT + (size_t)(n0 + r * 64 + lrow) * K + k0 + lseg * 8;
      __builtin_amdgcn_global_load_lds((const AS1 void*)gB,
          (AS3 void*)(Bs + r * 2048 + wave * 512), 16, 0, 0);
    }
    __syncthreads();
    s16x8 af[4], bfr[4];
    #pragma unroll
    for (int m = 0; m < 4; m++)
      af[m] = *(const s16x8*)(As + (wr * 64 + m * 16 + (lane & 15)) * 32 + (lane >> 4) * 8);
    #pragma unroll
    for (int n = 0; n < 4; n++)
      bfr[n] = *(const s16x8*)(Bs + (wc * 64 + n * 16 + (lane & 15)) * 32 + (lane >> 4) * 8);
    #pragma unroll
    for (int m = 0; m < 4; m++)
      #pragma unroll
      for (int n = 0; n < 4; n++)
        acc[m][n] = __builtin_amdgcn_mfma_f32_16x16x32_bf16(af[m], bfr[n], acc[m][n], 0, 0, 0);
  }
  #pragma unroll
  for (int m = 0; m < 4; m++) {
    int row = m0 + wr * 64 + m * 16 + (lane >> 4) * 4;
    #pragma unroll
    for (int n = 0; n < 4; n++) {
      int col = n0 + wc * 64 + n * 16 + (lane & 15);
      float* cp = C + (size_t)row * N + col;
      #pragma unroll
      for (int j = 0; j < 4; j++) cp[(size_t)j * N] = acc[m][n][j];
    }
  }
}

// ---------------- RMSnorm + RoPE + gain(+score scale) for q,k; write bf16 ----------------
__global__ __launch_bounds__(256) void qkpost_kernel(const float* __restrict__ QKV,
    const float* __restrict__ cosT, const float* __restrict__ sinT,
    const float* __restrict__ qgain, u16* __restrict__ Qbf, u16* __restrict__ Kbf) {
  int bt = blockIdx.x; int b = bt >> 11, t = bt & 2047;
  int lane = threadIdx.x & 63, wave = threadIdx.x >> 6;
  for (int u = wave; u < 20; u += 4) {
    const float* src = (u < 16) ? (QKV + (size_t)bt * 3072 + u * 128)
                                : (QKV + (size_t)bt * 3072 + 2048 + (u - 16) * 128);
    float x0 = src[lane], x1 = src[lane + 64];
    float ss = redsum64(x0 * x0 + x1 * x1);
    float r = 1.0f / sqrtf(ss * (1.0f / 128.0f) + 1.1920929e-7f);
    x0 *= r; x1 *= r;
    // rope: dims 0..63 live in x0 across the 64 lanes
    float partner = __shfl_xor(x0, 32);
    int i = lane & 31;
    float c = cosT[t * 32 + i], s = sinT[t * 32 + i];
    x0 = x0 * c + ((lane < 32) ? partner * s : -partner * s);
    if (u < 16) {
      float g = qgain[u] * 0.08838834764831845f; // fold score scale into Q
      x0 *= g; x1 *= g;
      u16* dst = Qbf + ((size_t)(b * 16 + u) * 2048 + t) * 128;
      dst[lane] = f2bf(x0); dst[lane + 64] = f2bf(x1);
    } else {
      u16* dst = Kbf + ((size_t)(b * 4 + (u - 16)) * 2048 + t) * 128;
      dst[lane] = f2bf(x0); dst[lane + 64] = f2bf(x1);
    }
  }
}

// ---------------- transpose V into (b,kh,d,t) bf16 ----------------
__global__ void transv_kernel(const float* __restrict__ QKV, u16* __restrict__ Vt) {
  __shared__ float tile[32][33];
  int t0 = blockIdx.x * 32, d0 = blockIdx.y * 32, bh = blockIdx.z;
  int b = bh >> 2, kh = bh & 3;
  int tx = threadIdx.x, ty = threadIdx.y;
  #pragma unroll
  for (int i = 0; i < 4; i++) {
    int t = t0 + ty + i * 8;
    tile[ty + i * 8][tx] = QKV[((size_t)(b * 2048 + t)) * 3072 + 2560 + kh * 128 + d0 + tx];
  }
  __syncthreads();
  #pragma unroll
  for (int i = 0; i < 4; i++) {
    int d = d0 + ty + i * 8;
    Vt[((size_t)bh * 128 + d) * 2048 + t0 + tx] = f2bf(tile[tx][ty + i * 8]);
  }
}

// ---------------- attention helpers ----------------
__device__ __forceinline__ void load_tile(const u16* Kg, const u16* Vg, int kv0,
    int tid, f32x4* kreg, f32x4* vreg) {
  #pragma unroll
  for (int it = 0; it < 4; it++) {
    int u = it * 256 + tid;
    kreg[it] = *(const f32x4*)(Kg + (size_t)(kv0 + (u >> 4)) * 128 + (u & 15) * 8);
    vreg[it] = *(const f32x4*)(Vg + (size_t)(u >> 3) * 2048 + kv0 + (u & 7) * 8);
  }
}
__device__ __forceinline__ void write_tile(u16* Ks, u16* Vts, int tid,
    const f32x4* kreg, const f32x4* vreg) {
  #pragma unroll
  for (int it = 0; it < 4; it++) {
    int u = it * 256 + tid;
    int krow = u >> 4, kseg = u & 15;
    *(f32x4*)((char*)Ks + ((krow * 256 + kseg * 16) ^ ((krow & 7) << 4))) = kreg[it];
    int d = u >> 3, vseg = u & 7;
    *(f32x4*)((char*)Vts + ((d * 128 + vseg * 16) ^ ((d & 7) << 4))) = vreg[it];
  }
}

// static-max softmax step: no cross-lane reductions, no rescale.
__device__ __forceinline__ void attn_step(const s16x8* qf, f32x4* yacc,
    float* l_part, const u16* Ks, const u16* Vts, u16* Pbuf,
    int kv0, int qbase, int lane, int wave, bool diag, float m_st) {
  f32x4 S[4];
  __builtin_amdgcn_s_setprio(1);
  #pragma unroll
  for (int nb = 0; nb < 4; nb++) {
    int kcol = nb * 16 + (lane & 15);
    f32x4 s = {};
    #pragma unroll
    for (int kb = 0; kb < 4; kb++) {
      int byt = (kcol * 256 + kb * 64 + (lane >> 4) * 16) ^ ((kcol & 7) << 4);
      s16x8 kf = *(const s16x8*)((const char*)Ks + byt);
      s = __builtin_amdgcn_mfma_f32_16x16x32_bf16(qf[kb], kf, s, 0, 0, 0);
    }
    S[nb] = s;
  }
  __builtin_amdgcn_s_setprio(0);
  if (diag) {
    #pragma unroll
    for (int nb = 0; nb < 4; nb++) {
      int kcol = kv0 + nb * 16 + (lane & 15);
      #pragma unroll
      for (int jj = 0; jj < 4; jj++) {
        int qr = qbase + wave * 16 + (lane >> 4) * 4 + jj;
        if (kcol > qr) S[nb][jj] = -1e30f;
      }
    }
  }
  // P = exp(S - m_static); |S| <= m_static by Cauchy-Schwarz (rows RMS-normed)
  #pragma unroll
  for (int nb = 0; nb < 4; nb++) {
    #pragma unroll
    for (int jj = 0; jj < 4; jj++) {
      float pv = __expf(S[nb][jj] - m_st);
      l_part[jj] += pv;
      int prow = (lane >> 4) * 4 + jj, pcol = nb * 16 + (lane & 15);
      int pbyte = (prow * 128 + pcol * 2) ^ ((prow & 7) << 4);
      *(u16*)((char*)Pbuf + pbyte) = f2bf(pv);
    }
  }
  s16x8 pa[2];
  #pragma unroll
  for (int k2 = 0; k2 < 2; k2++) {
    int prow = lane & 15;
    int pbyte = (prow * 128 + k2 * 64 + (lane >> 4) * 16) ^ ((prow & 7) << 4);
    pa[k2] = *(const s16x8*)((const char*)Pbuf + pbyte);
  }
  __builtin_amdgcn_s_setprio(1);
  #pragma unroll
  for (int nb = 0; nb < 8; nb++) {
    f32x4 y = yacc[nb];
    #pragma unroll
    for (int k2 = 0; k2 < 2; k2++) {
      int d = nb * 16 + (lane & 15);
      int vbyte = (d * 128 + k2 * 64 + (lane >> 4) * 16) ^ ((d & 7) << 4);
      s16x8 vf = *(const s16x8*)((const char*)Vts + vbyte);
      y = __builtin_amdgcn_mfma_f32_16x16x32_bf16(pa[k2], vf, y, 0, 0, 0);
    }
    yacc[nb] = y;
  }
  __builtin_amdgcn_s_setprio(0);
}

// ---------------- flash attention: causal GQA, folded q-tile pairs ----------------
// block = (pair p, head h, batch b); handles q-tiles p and 31-p; KV tiles shared.
// K/V double-buffered in LDS -> one barrier per tile step.
__global__ __launch_bounds__(256, 2) void attn_kernel(
    const u16* __restrict__ Qbf, const u16* __restrict__ Kbf,
    const u16* __restrict__ Vt, const float* __restrict__ qgain,
    u16* __restrict__ Ybf) {
  __shared__ __attribute__((aligned(16))) u16 Ks[2][64 * 128];   // [kv][d]  ^((kv&7)<<4)
  __shared__ __attribute__((aligned(16))) u16 Vts[2][128 * 64];  // [d][kv]  ^((d&7)<<4)
  __shared__ __attribute__((aligned(16))) u16 Pl[4][2][1024];    // per-wave, per-tile
  int p = blockIdx.x, h = blockIdx.y, b = blockIdx.z;
  int kh = h >> 2;
  int tid = threadIdx.x, lane = tid & 63, wave = tid >> 6;
  const int qiA = p, qiB = 31 - p;
  const int qbaseA = qiA * 64, qbaseB = qiB * 64;
  const u16* Qg = Qbf + ((size_t)(b * 16 + h) * 2048) * 128;
  const u16* Kg = Kbf + ((size_t)(b * 4 + kh) * 2048) * 128;
  const u16* Vg = Vt + ((size_t)(b * 4 + kh) * 128) * 2048;
  // |S| <= scale*|g|*||q_hat||*||k_hat|| = |g|*11.3137; +1% bf16 margin
  const float m_st = 11.427f * fabsf(qgain[h]);
  int qrA = qbaseA + wave * 16 + (lane & 15);
  int qrB = qbaseB + wave * 16 + (lane & 15);
  s16x8 qfA[4], qfB[4];
  #pragma unroll
  for (int kb = 0; kb < 4; kb++) {
    qfA[kb] = *(const s16x8*)(Qg + (size_t)qrA * 128 + kb * 32 + (lane >> 4) * 8);
    qfB[kb] = *(const s16x8*)(Qg + (size_t)qrB * 128 + kb * 32 + (lane >> 4) * 8);
  }
  f32x4 yA[8] = {}, yB[8] = {};
  float lA[4] = {}, lB[4] = {};
  f32x4 kreg[4], vreg[4];
  const int jmax = qiB;
  load_tile(Kg, Vg, 0, tid, kreg, vreg);
  write_tile(&Ks[0][0], &Vts[0][0], tid, kreg, vreg);
  load_tile(Kg, Vg, 64, tid, kreg, vreg);
  __syncthreads();
  for (int j = 0; j <= jmax; j++) {
    int cur = j & 1, kv0 = j * 64;
    if (j < jmax) {
      write_tile(&Ks[cur ^ 1][0], &Vts[cur ^ 1][0], tid, kreg, vreg);
      if (j + 2 <= jmax) load_tile(Kg, Vg, (j + 2) * 64, tid, kreg, vreg);
    }
    attn_step(qfB, yB, lB, &Ks[cur][0], &Vts[cur][0], &Pl[wave][1][0],
              kv0, qbaseB, lane, wave, j == qiB, m_st);
    if (j <= qiA)
      attn_step(qfA, yA, lA, &Ks[cur][0], &Vts[cur][0], &Pl[wave][0][0],
                kv0, qbaseA, lane, wave, j == qiA, m_st);
    __syncthreads();
  }
  #pragma unroll
  for (int jj = 0; jj < 4; jj++) {
    float linvB = 1.0f / redsum16(lB[jj]);
    int qr = qbaseB + wave * 16 + (lane >> 4) * 4 + jj;
    size_t ybase = ((size_t)(b * 16 + h) * 2048 + qr) * 128;
    #pragma unroll
    for (int nb = 0; nb < 8; nb++)
      Ybf[ybase + nb * 16 + (lane & 15)] = f2bf(yB[nb][jj] * linvB);
  }
  #pragma unroll
  for (int jj = 0; jj < 4; jj++) {
    float linvA = 1.0f / redsum16(lA[jj]);
    int qr = qbaseA + wave * 16 + (lane >> 4) * 4 + jj;
    size_t ybase = ((size_t)(b * 16 + h) * 2048 + qr) * 128;
    #pragma unroll
    for (int nb = 0; nb < 8; nb++)
      Ybf[ybase + nb * 16 + (lane & 15)] = f2bf(yA[nb][jj] * linvA);
  }
}

// ---------------- projection removal: y - (y.vn)vn; write (b,t,h*128+d) bf16 ----------------
__global__ __launch_bounds__(256) void projrm_kernel(const float* __restrict__ QKV,
    const u16* __restrict__ Ybf, u16* __restrict__ Yout) {
  int bt = blockIdx.x;
  int b = bt >> 11, t = bt & 2047;
  int lane = threadIdx.x & 63, kh = threadIdx.x >> 6;
  const float* v = QKV + (size_t)bt * 3072 + 2560 + kh * 128;
  float v0 = v[lane], v1 = v[lane + 64];
  float sv = redsum64(v0 * v0 + v1 * v1);
  float denom = fmaxf(sqrtf(sv), 1e-12f);
  float inv2 = 1.0f / (denom * denom);
  #pragma unroll
  for (int g = 0; g < 4; g++) {
    int h = kh * 4 + g;
    const u16* y = Ybf + ((size_t)(b * 16 + h) * 2048 + t) * 128;
    float y0 = bf2f(y[lane]), y1 = bf2f(y[lane + 64]);
    float c = redsum64(y0 * v0 + y1 * v1) * inv2;
    u16* o = Yout + (size_t)bt * 2048 + h * 128;
    o[lane] = f2bf(y0 - c * v0);
    o[lane + 64] = f2bf(y1 - c * v1);
  }
}

// ---------------- launch ----------------
extern "C" void kernel_launch(void* const* d_in, const int* in_sizes, int n_in,
                              void* d_out, int out_size, void* d_ws, size_t ws_size,
                              hipStream_t stream) {
  const float* x = (const float*)d_in[0];
  const float* Wq = (const float*)d_in[1];
  const float* Wk = (const float*)d_in[2];
  const float* Wv = (const float*)d_in[3];
  const float* Wp = (const float*)d_in[4];
  const float* qgain = (const float*)d_in[5];
  const float* qA = (const float*)d_in[6];
  const float* qB = (const float*)d_in[7];
  const float* kA = (const float*)d_in[8];
  const float* kB = (const float*)d_in[9];
  const float* vA = (const float*)d_in[10];
  const float* vB = (const float*)d_in[11];
  const float* pA = (const float*)d_in[12];
  const float* pB = (const float*)d_in[13];

  char* ws = (char*)d_ws;
  const size_t XBF  = 0;                  // 16777216  x bf16 [4096][2048]
  const size_t WQKV = 16777216;           // 12582912  [3072][2048] bf16 (q|k|v cols transposed)
  const size_t WPE  = 29360128;           // 8388608   [2048][2048] bf16
  const size_t QKV  = 37748736;           // 50331648  fp32 [4096][3072]
  const size_t COS  = 88080384;           // 262144
  const size_t SIN  = 88342528;           // 262144
  const size_t QBF  = 88604672;           // 16777216  (b,h,t,d)
  const size_t KBF  = 105381888;          // 4194304   (b,kh,t,d)
  const size_t VT   = 109576192;          // 4194304   (b,kh,d,t)
  const size_t YBF  = 113770496;          // 16777216  (b,h,t,d)
  const size_t YOUT = 130547712;          // 16777216  (b,t,h*128+d)

  u16* xbf = (u16*)(ws + XBF);
  u16* wqkv = (u16*)(ws + WQKV);
  u16* wpe = (u16*)(ws + WPE);
  float* qkv = (float*)(ws + QKV);
  float* cosT = (float*)(ws + COS);
  float* sinT = (float*)(ws + SIN);
  u16* qbf = (u16*)(ws + QBF);
  u16* kbf = (u16*)(ws + KBF);
  u16* vt = (u16*)(ws + VT);
  u16* ybf = (u16*)(ws + YBF);
  u16* yout = (u16*)(ws + YOUT);

  cast_x_kernel<<<8192, 256, 0, stream>>>(x, xbf, 2097152);
  rope_table_kernel<<<256, 256, 0, stream>>>(cosT, sinT);
  fuse_w_kernel<<<dim3(64, 64), dim3(32, 8), 0, stream>>>(Wq, qA, qB, wqkv, 2048);
  fuse_w_kernel<<<dim3(64, 16), dim3(32, 8), 0, stream>>>(Wk, kA, kB, wqkv + (size_t)2048 * 2048, 512);
  fuse_w_kernel<<<dim3(64, 16), dim3(32, 8), 0, stream>>>(Wv, vA, vB, wqkv + (size_t)2560 * 2048, 512);
  fuse_w_kernel<<<dim3(64, 64), dim3(32, 8), 0, stream>>>(Wp, pA, pB, wpe, 2048);
  gemm_kernel<<<dim3(32, 24), 256, 0, stream>>>(xbf, wqkv, qkv, 4096, 3072, 2048);
  qkpost_kernel<<<4096, 256, 0, stream>>>(qkv, cosT, sinT, qgain, qbf, kbf);
  transv_kernel<<<dim3(64, 4, 8), dim3(32, 8), 0, stream>>>(qkv, vt);
  attn_kernel<<<dim3(16, 16, 2), 256, 0, stream>>>(qbf, kbf, vt, qgain, ybf);
  projrm_kernel<<<4096, 256, 0, stream>>>(qkv, ybf, yout);
  gemm_kernel<<<dim3(32, 16), 256, 0, stream>>>(yout, wpe, (float*)d_out, 4096, 2048, 2048);
}

// Round 7
// 393.642 us; speedup vs baseline: 1.3155x; 1.0497x over previous
//
#include <hip/hip_runtime.h>

typedef unsigned short u16;
typedef __attribute__((ext_vector_type(4))) float f32x4;
typedef __attribute__((ext_vector_type(8))) short s16x8;
typedef __attribute__((ext_vector_type(4))) u16 u16x4;

#define AS1 __attribute__((address_space(1)))
#define AS3 __attribute__((address_space(3)))

__device__ inline u16 f2bf(float f) {
  union { float f; unsigned u; } v; v.f = f;
  unsigned r = v.u + 0x7FFFu + ((v.u >> 16) & 1u);
  return (u16)(r >> 16);
}
__device__ inline float bf2f(u16 h) {
  union { unsigned u; float f; } v; v.u = ((unsigned)h) << 16; return v.f;
}

__device__ inline float redsum16(float v) {
  v += __shfl_xor(v, 1); v += __shfl_xor(v, 2);
  v += __shfl_xor(v, 4); v += __shfl_xor(v, 8);
  return v;
}
__device__ inline float redsum64(float v) {
  v += __shfl_xor(v, 1); v += __shfl_xor(v, 2); v += __shfl_xor(v, 4);
  v += __shfl_xor(v, 8); v += __shfl_xor(v, 16); v += __shfl_xor(v, 32);
  return v;
}

// ---------------- cast x to bf16 ----------------
__global__ void cast_x_kernel(const float* __restrict__ x, u16* __restrict__ xbf, int n4) {
  int i = blockIdx.x * blockDim.x + threadIdx.x;
  if (i < n4) {
    f32x4 v = ((const f32x4*)x)[i];
    u16x4 o; o.x = f2bf(v.x); o.y = f2bf(v.y); o.z = f2bf(v.z); o.w = f2bf(v.w);
    ((u16x4*)xbf)[i] = o;
  }
}

// ---------------- rope table: cos/sin [T=2048][32] ----------------
__global__ void rope_table_kernel(float* __restrict__ cosT, float* __restrict__ sinT) {
  int idx = blockIdx.x * 256 + threadIdx.x; // 65536 = 2048*32
  int t = idx >> 5, i = idx & 31;
  float invf = (float)pow(10000.0, -(double)i / 32.0);
  float freq = (float)t * invf;
  cosT[idx] = (float)cos((double)freq);
  sinT[idx] = (float)sin((double)freq);
}

// ---------------- fuse W + A@B, write transposed bf16 [N][2048] ----------------
__global__ void fuse_w_kernel(const float* __restrict__ W, const float* __restrict__ A,
                              const float* __restrict__ Bl, u16* __restrict__ dstT, int N) {
  __shared__ float tile[32][33];
  int k0 = blockIdx.x * 32, n0 = blockIdx.y * 32;
  int tx = threadIdx.x, ty = threadIdx.y; // (32,8)
  #pragma unroll
  for (int i = 0; i < 4; i++) {
    int row = k0 + ty + i * 8;
    float s = W[(size_t)row * N + n0 + tx];
    #pragma unroll
    for (int r = 0; r < 16; r++) s += A[row * 16 + r] * Bl[r * N + n0 + tx];
    tile[ty + i * 8][tx] = s;
  }
  __syncthreads();
  #pragma unroll
  for (int i = 0; i < 4; i++) {
    int n = n0 + ty + i * 8;
    dstT[(size_t)n * 2048 + k0 + tx] = f2bf(tile[tx][ty + i * 8]);
  }
}

// ---------------- GEMM: C[M][N] fp32 = A[M][K]bf16 * BT[N][K]bf16 ----------------
// 3-buffer counted-vmcnt pipeline, BK=32, 128x128 tile, 4 waves.
// Per K-tile: vmcnt(4) -> raw barrier -> stage kt+2 -> swizzled ds_read -> 16 MFMA.
__global__ __launch_bounds__(256) void gemm_kernel(const u16* __restrict__ A,
    const u16* __restrict__ BT, float* __restrict__ C, int M, int N, int K, int nn) {
  __shared__ __attribute__((aligned(16))) u16 As[3][128 * 32];
  __shared__ __attribute__((aligned(16))) u16 Bs[3][128 * 32];
  const int tid = threadIdx.x;
  const int lane = tid & 63, wave = tid >> 6;
  const int wr = wave >> 1, wc = wave & 1;
  // XCD-aware bijective swizzle (grid % 8 == 0 guaranteed by launch)
  const int cpx = gridDim.x >> 3;
  const int wg = (blockIdx.x & 7) * cpx + (blockIdx.x >> 3);
  const int m0 = (wg / nn) * 128, n0 = (wg % nn) * 128;
  f32x4 acc[4][4] = {};
  const int NKT = K >> 5;
  // staging: thread covers 16B; row = r*64 + (tid>>2); source col-slot XORed by row&3
  const int srow = tid >> 2, sslot = tid & 3;
  const int scol0 = ((sslot ^ (srow & 3)) << 3);
  const u16* gA0 = A + (size_t)(m0 + srow) * K + scol0;
  const u16* gA1 = gA0 + (size_t)64 * K;
  const u16* gB0 = BT + (size_t)(n0 + srow) * K + scol0;
  const u16* gB1 = gB0 + (size_t)64 * K;
  // frag-read swizzle: slot = (lane>>4) ^ (row&3), row&3 == lane&3 here
  const int rslot = (((lane >> 4) ^ (lane & 3)) << 3);
  const int arow = wr * 64 + (lane & 15);
  const int brow = wc * 64 + (lane & 15);
  // prologue: stage kt0 -> buf0, kt1 -> buf1 (4 loads each, A0,A1,B0,B1 order)
  #pragma unroll
  for (int kt = 0; kt < 2; kt++) {
    __builtin_amdgcn_global_load_lds((const AS1 void*)(gA0 + kt * 32),
        (AS3 void*)(&As[kt][0] + wave * 512), 16, 0, 0);
    __builtin_amdgcn_global_load_lds((const AS1 void*)(gA1 + kt * 32),
        (AS3 void*)(&As[kt][2048] + wave * 512), 16, 0, 0);
    __builtin_amdgcn_global_load_lds((const AS1 void*)(gB0 + kt * 32),
        (AS3 void*)(&Bs[kt][0] + wave * 512), 16, 0, 0);
    __builtin_amdgcn_global_load_lds((const AS1 void*)(gB1 + kt * 32),
        (AS3 void*)(&Bs[kt][2048] + wave * 512), 16, 0, 0);
  }
  int buf = 0, sbuf = 2;
  for (int kt = 0; kt < NKT; kt++) {
    if (kt < NKT - 1) {
      asm volatile("s_waitcnt vmcnt(4)" ::: "memory");
    } else {
      asm volatile("s_waitcnt vmcnt(0)" ::: "memory");
    }
    // raw barrier WITH memory clobber: pins ds_reads/staging to program order
    asm volatile("s_barrier" ::: "memory");
    if (kt + 2 < NKT) {
      const int ko = (kt + 2) * 32;
      __builtin_amdgcn_global_load_lds((const AS1 void*)(gA0 + ko),
          (AS3 void*)(&As[sbuf][0] + wave * 512), 16, 0, 0);
      __builtin_amdgcn_global_load_lds((const AS1 void*)(gA1 + ko),
          (AS3 void*)(&As[sbuf][2048] + wave * 512), 16, 0, 0);
      __builtin_amdgcn_global_load_lds((const AS1 void*)(gB0 + ko),
          (AS3 void*)(&Bs[sbuf][0] + wave * 512), 16, 0, 0);
      __builtin_amdgcn_global_load_lds((const AS1 void*)(gB1 + ko),
          (AS3 void*)(&Bs[sbuf][2048] + wave * 512), 16, 0, 0);
    }
    const u16* Ab = &As[buf][0];
    const u16* Bb = &Bs[buf][0];
    s16x8 af[4], bfr[4];
    #pragma unroll
    for (int m = 0; m < 4; m++)
      af[m] = *(const s16x8*)(Ab + (arow + m * 16) * 32 + rslot);
    #pragma unroll
    for (int n = 0; n < 4; n++)
      bfr[n] = *(const s16x8*)(Bb + (brow + n * 16) * 32 + rslot);
    __builtin_amdgcn_s_setprio(1);
    #pragma unroll
    for (int m = 0; m < 4; m++)
      #pragma unroll
      for (int n = 0; n < 4; n++)
        acc[m][n] = __builtin_amdgcn_mfma_f32_16x16x32_bf16(af[m], bfr[n], acc[m][n], 0, 0, 0);
    __builtin_amdgcn_s_setprio(0);
    sbuf = buf;
    buf = (buf == 2) ? 0 : buf + 1;
  }
  #pragma unroll
  for (int m = 0; m < 4; m++) {
    int row = m0 + wr * 64 + m * 16 + (lane >> 4) * 4;
    #pragma unroll
    for (int n = 0; n < 4; n++) {
      int col = n0 + wc * 64 + n * 16 + (lane & 15);
      float* cp = C + (size_t)row * N + col;
      #pragma unroll
      for (int j = 0; j < 4; j++) cp[(size_t)j * N] = acc[m][n][j];
    }
  }
}

// ---------------- RMSnorm + RoPE + gain(+score scale) for q,k; write bf16 ----------------
__global__ __launch_bounds__(256) void qkpost_kernel(const float* __restrict__ QKV,
    const float* __restrict__ cosT, const float* __restrict__ sinT,
    const float* __restrict__ qgain, u16* __restrict__ Qbf, u16* __restrict__ Kbf) {
  int bt = blockIdx.x; int b = bt >> 11, t = bt & 2047;
  int lane = threadIdx.x & 63, wave = threadIdx.x >> 6;
  for (int u = wave; u < 20; u += 4) {
    const float* src = (u < 16) ? (QKV + (size_t)bt * 3072 + u * 128)
                                : (QKV + (size_t)bt * 3072 + 2048 + (u - 16) * 128);
    float x0 = src[lane], x1 = src[lane + 64];
    float ss = redsum64(x0 * x0 + x1 * x1);
    float r = 1.0f / sqrtf(ss * (1.0f / 128.0f) + 1.1920929e-7f);
    x0 *= r; x1 *= r;
    // rope: dims 0..63 live in x0 across the 64 lanes
    float partner = __shfl_xor(x0, 32);
    int i = lane & 31;
    float c = cosT[t * 32 + i], s = sinT[t * 32 + i];
    x0 = x0 * c + ((lane < 32) ? partner * s : -partner * s);
    if (u < 16) {
      float g = qgain[u] * 0.08838834764831845f; // fold score scale into Q
      x0 *= g; x1 *= g;
      u16* dst = Qbf + ((size_t)(b * 16 + u) * 2048 + t) * 128;
      dst[lane] = f2bf(x0); dst[lane + 64] = f2bf(x1);
    } else {
      u16* dst = Kbf + ((size_t)(b * 4 + (u - 16)) * 2048 + t) * 128;
      dst[lane] = f2bf(x0); dst[lane + 64] = f2bf(x1);
    }
  }
}

// ---------------- transpose V into (b,kh,d,t) bf16 ----------------
__global__ void transv_kernel(const float* __restrict__ QKV, u16* __restrict__ Vt) {
  __shared__ float tile[32][33];
  int t0 = blockIdx.x * 32, d0 = blockIdx.y * 32, bh = blockIdx.z;
  int b = bh >> 2, kh = bh & 3;
  int tx = threadIdx.x, ty = threadIdx.y;
  #pragma unroll
  for (int i = 0; i < 4; i++) {
    int t = t0 + ty + i * 8;
    tile[ty + i * 8][tx] = QKV[((size_t)(b * 2048 + t)) * 3072 + 2560 + kh * 128 + d0 + tx];
  }
  __syncthreads();
  #pragma unroll
  for (int i = 0; i < 4; i++) {
    int d = d0 + ty + i * 8;
    Vt[((size_t)bh * 128 + d) * 2048 + t0 + tx] = f2bf(tile[tx][ty + i * 8]);
  }
}

// ---------------- attention helpers ----------------
__device__ __forceinline__ void load_tile(const u16* Kg, const u16* Vg, int kv0,
    int tid, f32x4* kreg, f32x4* vreg) {
  #pragma unroll
  for (int it = 0; it < 4; it++) {
    int u = it * 256 + tid;
    kreg[it] = *(const f32x4*)(Kg + (size_t)(kv0 + (u >> 4)) * 128 + (u & 15) * 8);
    vreg[it] = *(const f32x4*)(Vg + (size_t)(u >> 3) * 2048 + kv0 + (u & 7) * 8);
  }
}
__device__ __forceinline__ void write_tile(u16* Ks, u16* Vts, int tid,
    const f32x4* kreg, const f32x4* vreg) {
  #pragma unroll
  for (int it = 0; it < 4; it++) {
    int u = it * 256 + tid;
    int krow = u >> 4, kseg = u & 15;
    *(f32x4*)((char*)Ks + ((krow * 256 + kseg * 16) ^ ((krow & 7) << 4))) = kreg[it];
    int d = u >> 3, vseg = u & 7;
    *(f32x4*)((char*)Vts + ((d * 128 + vseg * 16) ^ ((d & 7) << 4))) = vreg[it];
  }
}

// static-max softmax step: no cross-lane reductions, no rescale.
__device__ __forceinline__ void attn_step(const s16x8* qf, f32x4* yacc,
    float* l_part, const u16* Ks, const u16* Vts, u16* Pbuf,
    int kv0, int qbase, int lane, int wave, bool diag, float m_st) {
  f32x4 S[4];
  __builtin_amdgcn_s_setprio(1);
  #pragma unroll
  for (int nb = 0; nb < 4; nb++) {
    int kcol = nb * 16 + (lane & 15);
    f32x4 s = {};
    #pragma unroll
    for (int kb = 0; kb < 4; kb++) {
      int byt = (kcol * 256 + kb * 64 + (lane >> 4) * 16) ^ ((kcol & 7) << 4);
      s16x8 kf = *(const s16x8*)((const char*)Ks + byt);
      s = __builtin_amdgcn_mfma_f32_16x16x32_bf16(qf[kb], kf, s, 0, 0, 0);
    }
    S[nb] = s;
  }
  __builtin_amdgcn_s_setprio(0);
  if (diag) {
    #pragma unroll
    for (int nb = 0; nb < 4; nb++) {
      int kcol = kv0 + nb * 16 + (lane & 15);
      #pragma unroll
      for (int jj = 0; jj < 4; jj++) {
        int qr = qbase + wave * 16 + (lane >> 4) * 4 + jj;
        if (kcol > qr) S[nb][jj] = -1e30f;
      }
    }
  }
  // P = exp(S - m_static); |S| <= m_static by Cauchy-Schwarz (rows RMS-normed)
  #pragma unroll
  for (int nb = 0; nb < 4; nb++) {
    #pragma unroll
    for (int jj = 0; jj < 4; jj++) {
      float pv = __expf(S[nb][jj] - m_st);
      l_part[jj] += pv;
      int prow = (lane >> 4) * 4 + jj, pcol = nb * 16 + (lane & 15);
      int pbyte = (prow * 128 + pcol * 2) ^ ((prow & 7) << 4);
      *(u16*)((char*)Pbuf + pbyte) = f2bf(pv);
    }
  }
  s16x8 pa[2];
  #pragma unroll
  for (int k2 = 0; k2 < 2; k2++) {
    int prow = lane & 15;
    int pbyte = (prow * 128 + k2 * 64 + (lane >> 4) * 16) ^ ((prow & 7) << 4);
    pa[k2] = *(const s16x8*)((const char*)Pbuf + pbyte);
  }
  __builtin_amdgcn_s_setprio(1);
  #pragma unroll
  for (int nb = 0; nb < 8; nb++) {
    f32x4 y = yacc[nb];
    #pragma unroll
    for (int k2 = 0; k2 < 2; k2++) {
      int d = nb * 16 + (lane & 15);
      int vbyte = (d * 128 + k2 * 64 + (lane >> 4) * 16) ^ ((d & 7) << 4);
      s16x8 vf = *(const s16x8*)((const char*)Vts + vbyte);
      y = __builtin_amdgcn_mfma_f32_16x16x32_bf16(pa[k2], vf, y, 0, 0, 0);
    }
    yacc[nb] = y;
  }
  __builtin_amdgcn_s_setprio(0);
}

// ---------------- flash attention: causal GQA, folded q-tile pairs ----------------
// block = (pair p, head h, batch b); handles q-tiles p and 31-p; KV tiles shared.
// K/V double-buffered in LDS -> one barrier per tile step.
__global__ __launch_bounds__(256, 2) void attn_kernel(
    const u16* __restrict__ Qbf, const u16* __restrict__ Kbf,
    const u16* __restrict__ Vt, const float* __restrict__ qgain,
    u16* __restrict__ Ybf) {
  __shared__ __attribute__((aligned(16))) u16 Ks[2][64 * 128];   // [kv][d]  ^((kv&7)<<4)
  __shared__ __attribute__((aligned(16))) u16 Vts[2][128 * 64];  // [d][kv]  ^((d&7)<<4)
  __shared__ __attribute__((aligned(16))) u16 Pl[4][2][1024];    // per-wave, per-tile
  int p = blockIdx.x, h = blockIdx.y, b = blockIdx.z;
  int kh = h >> 2;
  int tid = threadIdx.x, lane = tid & 63, wave = tid >> 6;
  const int qiA = p, qiB = 31 - p;
  const int qbaseA = qiA * 64, qbaseB = qiB * 64;
  const u16* Qg = Qbf + ((size_t)(b * 16 + h) * 2048) * 128;
  const u16* Kg = Kbf + ((size_t)(b * 4 + kh) * 2048) * 128;
  const u16* Vg = Vt + ((size_t)(b * 4 + kh) * 128) * 2048;
  // |S| <= scale*|g|*||q_hat||*||k_hat|| = |g|*11.3137; +1% bf16 margin
  const float m_st = 11.427f * fabsf(qgain[h]);
  int qrA = qbaseA + wave * 16 + (lane & 15);
  int qrB = qbaseB + wave * 16 + (lane & 15);
  s16x8 qfA[4], qfB[4];
  #pragma unroll
  for (int kb = 0; kb < 4; kb++) {
    qfA[kb] = *(const s16x8*)(Qg + (size_t)qrA * 128 + kb * 32 + (lane >> 4) * 8);
    qfB[kb] = *(const s16x8*)(Qg + (size_t)qrB * 128 + kb * 32 + (lane >> 4) * 8);
  }
  f32x4 yA[8] = {}, yB[8] = {};
  float lA[4] = {}, lB[4] = {};
  f32x4 kreg[4], vreg[4];
  const int jmax = qiB;
  load_tile(Kg, Vg, 0, tid, kreg, vreg);
  write_tile(&Ks[0][0], &Vts[0][0], tid, kreg, vreg);
  load_tile(Kg, Vg, 64, tid, kreg, vreg);
  __syncthreads();
  for (int j = 0; j <= jmax; j++) {
    int cur = j & 1, kv0 = j * 64;
    if (j < jmax) {
      write_tile(&Ks[cur ^ 1][0], &Vts[cur ^ 1][0], tid, kreg, vreg);
      if (j + 2 <= jmax) load_tile(Kg, Vg, (j + 2) * 64, tid, kreg, vreg);
    }
    attn_step(qfB, yB, lB, &Ks[cur][0], &Vts[cur][0], &Pl[wave][1][0],
              kv0, qbaseB, lane, wave, j == qiB, m_st);
    if (j <= qiA)
      attn_step(qfA, yA, lA, &Ks[cur][0], &Vts[cur][0], &Pl[wave][0][0],
                kv0, qbaseA, lane, wave, j == qiA, m_st);
    __syncthreads();
  }
  #pragma unroll
  for (int jj = 0; jj < 4; jj++) {
    float linvB = 1.0f / redsum16(lB[jj]);
    int qr = qbaseB + wave * 16 + (lane >> 4) * 4 + jj;
    size_t ybase = ((size_t)(b * 16 + h) * 2048 + qr) * 128;
    #pragma unroll
    for (int nb = 0; nb < 8; nb++)
      Ybf[ybase + nb * 16 + (lane & 15)] = f2bf(yB[nb][jj] * linvB);
  }
  #pragma unroll
  for (int jj = 0; jj < 4; jj++) {
    float linvA = 1.0f / redsum16(lA[jj]);
    int qr = qbaseA + wave * 16 + (lane >> 4) * 4 + jj;
    size_t ybase = ((size_t)(b * 16 + h) * 2048 + qr) * 128;
    #pragma unroll
    for (int nb = 0; nb < 8; nb++)
      Ybf[ybase + nb * 16 + (lane & 15)] = f2bf(yA[nb][jj] * linvA);
  }
}

// ---------------- projection removal: y - (y.vn)vn; write (b,t,h*128+d) bf16 ----------------
__global__ __launch_bounds__(256) void projrm_kernel(const float* __restrict__ QKV,
    const u16* __restrict__ Ybf, u16* __restrict__ Yout) {
  int bt = blockIdx.x;
  int b = bt >> 11, t = bt & 2047;
  int lane = threadIdx.x & 63, kh = threadIdx.x >> 6;
  const float* v = QKV + (size_t)bt * 3072 + 2560 + kh * 128;
  float v0 = v[lane], v1 = v[lane + 64];
  float sv = redsum64(v0 * v0 + v1 * v1);
  float denom = fmaxf(sqrtf(sv), 1e-12f);
  float inv2 = 1.0f / (denom * denom);
  #pragma unroll
  for (int g = 0; g < 4; g++) {
    int h = kh * 4 + g;
    const u16* y = Ybf + ((size_t)(b * 16 + h) * 2048 + t) * 128;
    float y0 = bf2f(y[lane]), y1 = bf2f(y[lane + 64]);
    float c = redsum64(y0 * v0 + y1 * v1) * inv2;
    u16* o = Yout + (size_t)bt * 2048 + h * 128;
    o[lane] = f2bf(y0 - c * v0);
    o[lane + 64] = f2bf(y1 - c * v1);
  }
}

// ---------------- launch ----------------
extern "C" void kernel_launch(void* const* d_in, const int* in_sizes, int n_in,
                              void* d_out, int out_size, void* d_ws, size_t ws_size,
                              hipStream_t stream) {
  const float* x = (const float*)d_in[0];
  const float* Wq = (const float*)d_in[1];
  const float* Wk = (const float*)d_in[2];
  const float* Wv = (const float*)d_in[3];
  const float* Wp = (const float*)d_in[4];
  const float* qgain = (const float*)d_in[5];
  const float* qA = (const float*)d_in[6];
  const float* qB = (const float*)d_in[7];
  const float* kA = (const float*)d_in[8];
  const float* kB = (const float*)d_in[9];
  const float* vA = (const float*)d_in[10];
  const float* vB = (const float*)d_in[11];
  const float* pA = (const float*)d_in[12];
  const float* pB = (const float*)d_in[13];

  char* ws = (char*)d_ws;
  const size_t XBF  = 0;                  // 16777216  x bf16 [4096][2048]
  const size_t WQKV = 16777216;           // 12582912  [3072][2048] bf16 (q|k|v cols transposed)
  const size_t WPE  = 29360128;           // 8388608   [2048][2048] bf16
  const size_t QKV  = 37748736;           // 50331648  fp32 [4096][3072]
  const size_t COS  = 88080384;           // 262144
  const size_t SIN  = 88342528;           // 262144
  const size_t QBF  = 88604672;           // 16777216  (b,h,t,d)
  const size_t KBF  = 105381888;          // 4194304   (b,kh,t,d)
  const size_t VT   = 109576192;          // 4194304   (b,kh,d,t)
  const size_t YBF  = 113770496;          // 16777216  (b,h,t,d)
  const size_t YOUT = 130547712;          // 16777216  (b,t,h*128+d)

  u16* xbf = (u16*)(ws + XBF);
  u16* wqkv = (u16*)(ws + WQKV);
  u16* wpe = (u16*)(ws + WPE);
  float* qkv = (float*)(ws + QKV);
  float* cosT = (float*)(ws + COS);
  float* sinT = (float*)(ws + SIN);
  u16* qbf = (u16*)(ws + QBF);
  u16* kbf = (u16*)(ws + KBF);
  u16* vt = (u16*)(ws + VT);
  u16* ybf = (u16*)(ws + YBF);
  u16* yout = (u16*)(ws + YOUT);

  cast_x_kernel<<<8192, 256, 0, stream>>>(x, xbf, 2097152);
  rope_table_kernel<<<256, 256, 0, stream>>>(cosT, sinT);
  fuse_w_kernel<<<dim3(64, 64), dim3(32, 8), 0, stream>>>(Wq, qA, qB, wqkv, 2048);
  fuse_w_kernel<<<dim3(64, 16), dim3(32, 8), 0, stream>>>(Wk, kA, kB, wqkv + (size_t)2048 * 2048, 512);
  fuse_w_kernel<<<dim3(64, 16), dim3(32, 8), 0, stream>>>(Wv, vA, vB, wqkv + (size_t)2560 * 2048, 512);
  fuse_w_kernel<<<dim3(64, 64), dim3(32, 8), 0, stream>>>(Wp, pA, pB, wpe, 2048);
  gemm_kernel<<<768, 256, 0, stream>>>(xbf, wqkv, qkv, 4096, 3072, 2048, 24);
  qkpost_kernel<<<4096, 256, 0, stream>>>(qkv, cosT, sinT, qgain, qbf, kbf);
  transv_kernel<<<dim3(64, 4, 8), dim3(32, 8), 0, stream>>>(qkv, vt);
  attn_kernel<<<dim3(16, 16, 2), 256, 0, stream>>>(qbf, kbf, vt, qgain, ybf);
  projrm_kernel<<<4096, 256, 0, stream>>>(qkv, ybf, yout);
  gemm_kernel<<<512, 256, 0, stream>>>(yout, wpe, (float*)d_out, 4096, 2048, 2048, 16);
}